// Round 1
// baseline (1895.518 us; speedup 1.0000x reference)
//
#include <hip/hip_runtime.h>

// ---------------------------------------------------------------------------
// f32 GEMM:  C[M,N] = A[M,K] * B[N,K]^T      (nn.Linear: y = x @ W.T)
// 128x128 tile, TK=32, 256 threads, 8x8 per thread (2x2 blocks of 4x4).
// ---------------------------------------------------------------------------
#define TM 128
#define TN 128
#define TK 32

__global__ __launch_bounds__(256, 2)
void gemm_nt(const float* __restrict__ A, const float* __restrict__ B,
             float* __restrict__ C, int M, int N, int K)
{
    __shared__ float As[TK][TM + 4];   // transposed: As[k][m]
    __shared__ float Bs[TK][TN + 4];   // transposed: Bs[k][n]

    const int t  = threadIdx.x;
    const int tx = t & 15;             // 0..15 -> n sub-col
    const int ty = t >> 4;             // 0..15 -> m sub-row
    const int m0 = blockIdx.x * TM;
    const int n0 = blockIdx.y * TN;

    const float* Ap = A + (size_t)m0 * K;
    const float* Bp = B + (size_t)n0 * K;

    float acc[2][2][4][4] = {};        // [mi][ni][r][c]

    for (int k0 = 0; k0 < K; k0 += TK) {
        // stage A,B tiles (128x32) into LDS, transposed to [k][m]/[k][n]
        #pragma unroll
        for (int i = 0; i < 4; i++) {
            int id = t + 256 * i;
            int r  = id >> 3;          // 0..127 row in tile
            int c  = id & 7;           // float4 col 0..7
            float4 va = *(const float4*)(Ap + (size_t)r * K + k0 + c * 4);
            As[c*4+0][r] = va.x; As[c*4+1][r] = va.y;
            As[c*4+2][r] = va.z; As[c*4+3][r] = va.w;
            float4 vb = *(const float4*)(Bp + (size_t)r * K + k0 + c * 4);
            Bs[c*4+0][r] = vb.x; Bs[c*4+1][r] = vb.y;
            Bs[c*4+2][r] = vb.z; Bs[c*4+3][r] = vb.w;
        }
        __syncthreads();

        #pragma unroll 8
        for (int k = 0; k < TK; k++) {
            float a[2][4], b[2][4];
            #pragma unroll
            for (int mi = 0; mi < 2; mi++) {
                float4 v = *(const float4*)&As[k][mi*64 + ty*4];
                a[mi][0]=v.x; a[mi][1]=v.y; a[mi][2]=v.z; a[mi][3]=v.w;
            }
            #pragma unroll
            for (int ni = 0; ni < 2; ni++) {
                float4 v = *(const float4*)&Bs[k][ni*64 + tx*4];
                b[ni][0]=v.x; b[ni][1]=v.y; b[ni][2]=v.z; b[ni][3]=v.w;
            }
            #pragma unroll
            for (int mi = 0; mi < 2; mi++)
            #pragma unroll
            for (int r = 0; r < 4; r++)
            #pragma unroll
            for (int ni = 0; ni < 2; ni++)
            #pragma unroll
            for (int c = 0; c < 4; c++)
                acc[mi][ni][r][c] = fmaf(a[mi][r], b[ni][c], acc[mi][ni][r][c]);
        }
        __syncthreads();
    }

    #pragma unroll
    for (int mi = 0; mi < 2; mi++)
    #pragma unroll
    for (int r = 0; r < 4; r++) {
        int row = m0 + mi*64 + ty*4 + r;
        #pragma unroll
        for (int ni = 0; ni < 2; ni++) {
            float4 v;
            v.x = acc[mi][ni][r][0]; v.y = acc[mi][ni][r][1];
            v.z = acc[mi][ni][r][2]; v.w = acc[mi][ni][r][3];
            *(float4*)(C + (size_t)row * N + n0 + ni*64 + tx*4) = v;
        }
    }
}

// ---------------------------------------------------------------------------
// Flash-style attention, f32. One block = (b, h, 64 q-rows). Dk = 64.
// Thread (tx,ty): S-phase owns rows ty*4+r, cols tx+16c (strided, bank-clean);
//                 O-phase owns rows ty*4+r, d-cols tx*4+j.
// ---------------------------------------------------------------------------
__global__ __launch_bounds__(256, 2)
void attn64(const float* __restrict__ Q, const float* __restrict__ Kp,
            const float* __restrict__ Vp, const int* __restrict__ mask,
            float* __restrict__ O)
{
    const int S = 2048, E = 1024, DK = 64;
    __shared__ float Qs[64][68];
    __shared__ float Ks[64][68];
    __shared__ float Vs[64][68];
    __shared__ float Ps[64][68];

    const int t  = threadIdx.x;
    const int tx = t & 15;
    const int ty = t >> 4;
    const int q0 = blockIdx.x * 64;
    const int h  = blockIdx.y;
    const int b  = blockIdx.z;
    const size_t base = (size_t)b * S * E + (size_t)h * DK;

    // stage Q tile (64 x 64)
    #pragma unroll
    for (int i = 0; i < 4; i++) {
        int id = t + 256 * i;
        int r = id >> 4, c = id & 15;
        *(float4*)&Qs[r][c*4] =
            *(const float4*)(Q + base + (size_t)(q0 + r) * E + c * 4);
    }

    float m[4], l[4], acc[4][4];
    #pragma unroll
    for (int r = 0; r < 4; r++) {
        m[r] = -1e30f; l[r] = 0.f;
        #pragma unroll
        for (int j = 0; j < 4; j++) acc[r][j] = 0.f;
    }

    for (int k0 = 0; k0 < S; k0 += 64) {
        // stage K,V tiles
        #pragma unroll
        for (int i = 0; i < 4; i++) {
            int id = t + 256 * i;
            int r = id >> 4, c = id & 15;
            *(float4*)&Ks[r][c*4] =
                *(const float4*)(Kp + base + (size_t)(k0 + r) * E + c * 4);
            *(float4*)&Vs[r][c*4] =
                *(const float4*)(Vp + base + (size_t)(k0 + r) * E + c * 4);
        }
        __syncthreads();   // K/V (and Qs on first iter) visible

        // S = Q K^T  (4x4 per thread)
        float s[4][4] = {};
        #pragma unroll 4
        for (int d0 = 0; d0 < DK; d0 += 4) {
            float a[4][4], bb[4][4];
            #pragma unroll
            for (int r = 0; r < 4; r++) {
                float4 v = *(const float4*)&Qs[ty*4 + r][d0];
                a[r][0]=v.x; a[r][1]=v.y; a[r][2]=v.z; a[r][3]=v.w;
            }
            #pragma unroll
            for (int c = 0; c < 4; c++) {
                float4 v = *(const float4*)&Ks[tx + 16*c][d0];
                bb[c][0]=v.x; bb[c][1]=v.y; bb[c][2]=v.z; bb[c][3]=v.w;
            }
            #pragma unroll
            for (int r = 0; r < 4; r++)
            #pragma unroll
            for (int c = 0; c < 4; c++)
            #pragma unroll
            for (int d = 0; d < 4; d++)
                s[r][c] = fmaf(a[r][d], bb[c][d], s[r][c]);
        }

        // scale + key-padding mask
        int mk[4];
        #pragma unroll
        for (int c = 0; c < 4; c++) mk[c] = mask[b * S + k0 + tx + 16*c];
        #pragma unroll
        for (int r = 0; r < 4; r++)
        #pragma unroll
        for (int c = 0; c < 4; c++)
            s[r][c] = mk[c] ? s[r][c] * 0.125f : -1e30f;

        // online softmax per row (16 lanes share a row)
        #pragma unroll
        for (int r = 0; r < 4; r++) {
            float tm = fmaxf(fmaxf(s[r][0], s[r][1]), fmaxf(s[r][2], s[r][3]));
            #pragma unroll
            for (int o = 1; o < 16; o <<= 1) tm = fmaxf(tm, __shfl_xor(tm, o));
            float mn   = fmaxf(m[r], tm);
            float corr = __expf(m[r] - mn);
            m[r] = mn;
            float rs = 0.f;
            #pragma unroll
            for (int c = 0; c < 4; c++) {
                float p = __expf(s[r][c] - mn);
                Ps[ty*4 + r][tx + 16*c] = p;
                rs += p;
            }
            #pragma unroll
            for (int o = 1; o < 16; o <<= 1) rs += __shfl_xor(rs, o);
            l[r] = l[r] * corr + rs;
            #pragma unroll
            for (int j = 0; j < 4; j++) acc[r][j] *= corr;
        }
        __syncthreads();   // Ps visible

        // O += P @ V
        #pragma unroll 4
        for (int k = 0; k < 64; k += 4) {
            float p[4][4];
            #pragma unroll
            for (int r = 0; r < 4; r++) {
                float4 v = *(const float4*)&Ps[ty*4 + r][k];
                p[r][0]=v.x; p[r][1]=v.y; p[r][2]=v.z; p[r][3]=v.w;
            }
            #pragma unroll
            for (int kk = 0; kk < 4; kk++) {
                float4 v = *(const float4*)&Vs[k + kk][tx*4];
                #pragma unroll
                for (int r = 0; r < 4; r++) {
                    acc[r][0] = fmaf(p[r][kk], v.x, acc[r][0]);
                    acc[r][1] = fmaf(p[r][kk], v.y, acc[r][1]);
                    acc[r][2] = fmaf(p[r][kk], v.z, acc[r][2]);
                    acc[r][3] = fmaf(p[r][kk], v.w, acc[r][3]);
                }
            }
        }
        __syncthreads();   // done with Ks/Vs/Ps before next overwrite
    }

    // epilogue: normalize and store (AO aliases Q scratch: this block owns
    // exactly the slice it read, and Q was consumed into LDS above)
    #pragma unroll
    for (int r = 0; r < 4; r++) {
        float inv = 1.0f / l[r];
        float4 v;
        v.x = acc[r][0]*inv; v.y = acc[r][1]*inv;
        v.z = acc[r][2]*inv; v.w = acc[r][3]*inv;
        *(float4*)(O + base + (size_t)(q0 + ty*4 + r) * E + tx*4) = v;
    }
}

// ---------------------------------------------------------------------------
extern "C" void kernel_launch(void* const* d_in, const int* in_sizes, int n_in,
                              void* d_out, int out_size, void* d_ws, size_t ws_size,
                              hipStream_t stream)
{
    const float* x    = (const float*)d_in[0];
    const int*   mask = (const int*)  d_in[1];
    const float* Wq   = (const float*)d_in[2];
    const float* Wk   = (const float*)d_in[3];
    const float* Wv   = (const float*)d_in[4];
    const float* Wo   = (const float*)d_in[5];
    float* out = (float*)d_out;
    float* ws  = (float*)d_ws;

    const int B = 4, S = 2048, E = 1024;
    const int M = B * S;                 // 8192
    const size_t SZ = (size_t)M * E;     // 8388608 floats = 32 MB

    float* Qb = ws;
    float* Kb = ws + SZ;
    float* Vb = ws + 2 * SZ;
    float* AO = Qb;                      // safe alias (see attn64 epilogue)

    dim3 tb(256);
    dim3 gg(M / TM, E / TN);             // 64 x 8

    gemm_nt<<<gg, tb, 0, stream>>>(x, Wq, Qb, M, E, E);
    gemm_nt<<<gg, tb, 0, stream>>>(x, Wk, Kb, M, E, E);
    gemm_nt<<<gg, tb, 0, stream>>>(x, Wv, Vb, M, E, E);

    dim3 ga(S / 64, 16, B);              // 32 x 16 x 4
    attn64<<<ga, tb, 0, stream>>>(Qb, Kb, Vb, mask, AO);

    gemm_nt<<<gg, tb, 0, stream>>>(AO, Wo, out, M, E, E);
}

// Round 2
// 1141.465 us; speedup vs baseline: 1.6606x; 1.6606x over previous
//
#include <hip/hip_runtime.h>

typedef __attribute__((ext_vector_type(8))) __bf16   bf16x8;
typedef __attribute__((ext_vector_type(4))) __bf16   bf16x4;
typedef __attribute__((ext_vector_type(8))) _Float16 f16x8;
typedef __attribute__((ext_vector_type(4))) float    f32x4;

#define MFMA_BF16 __builtin_amdgcn_mfma_f32_16x16x32_bf16
#define MFMA_F16  __builtin_amdgcn_mfma_f32_16x16x32_f16

// ---------------------------------------------------------------------------
// f32 GEMM:  C[M,N] = A[M,K] * B[N,K]^T      (nn.Linear: y = x @ W.T)
// 128x128 tile, TK=32, 256 threads, 8x8 per thread (2x2 blocks of 4x4).
// ---------------------------------------------------------------------------
#define TM 128
#define TN 128
#define TK 32

__global__ __launch_bounds__(256, 2)
void gemm_nt(const float* __restrict__ A, const float* __restrict__ B,
             float* __restrict__ C, int M, int N, int K)
{
    __shared__ float As[TK][TM + 4];   // transposed: As[k][m]
    __shared__ float Bs[TK][TN + 4];   // transposed: Bs[k][n]

    const int t  = threadIdx.x;
    const int tx = t & 15;
    const int ty = t >> 4;
    const int m0 = blockIdx.x * TM;
    const int n0 = blockIdx.y * TN;

    const float* Ap = A + (size_t)m0 * K;
    const float* Bp = B + (size_t)n0 * K;

    float acc[2][2][4][4] = {};

    for (int k0 = 0; k0 < K; k0 += TK) {
        #pragma unroll
        for (int i = 0; i < 4; i++) {
            int id = t + 256 * i;
            int r  = id >> 3;
            int c  = id & 7;
            float4 va = *(const float4*)(Ap + (size_t)r * K + k0 + c * 4);
            As[c*4+0][r] = va.x; As[c*4+1][r] = va.y;
            As[c*4+2][r] = va.z; As[c*4+3][r] = va.w;
            float4 vb = *(const float4*)(Bp + (size_t)r * K + k0 + c * 4);
            Bs[c*4+0][r] = vb.x; Bs[c*4+1][r] = vb.y;
            Bs[c*4+2][r] = vb.z; Bs[c*4+3][r] = vb.w;
        }
        __syncthreads();

        #pragma unroll 8
        for (int k = 0; k < TK; k++) {
            float a[2][4], b[2][4];
            #pragma unroll
            for (int mi = 0; mi < 2; mi++) {
                float4 v = *(const float4*)&As[k][mi*64 + ty*4];
                a[mi][0]=v.x; a[mi][1]=v.y; a[mi][2]=v.z; a[mi][3]=v.w;
            }
            #pragma unroll
            for (int ni = 0; ni < 2; ni++) {
                float4 v = *(const float4*)&Bs[k][ni*64 + tx*4];
                b[ni][0]=v.x; b[ni][1]=v.y; b[ni][2]=v.z; b[ni][3]=v.w;
            }
            #pragma unroll
            for (int mi = 0; mi < 2; mi++)
            #pragma unroll
            for (int r = 0; r < 4; r++)
            #pragma unroll
            for (int ni = 0; ni < 2; ni++)
            #pragma unroll
            for (int c = 0; c < 4; c++)
                acc[mi][ni][r][c] = fmaf(a[mi][r], b[ni][c], acc[mi][ni][r][c]);
        }
        __syncthreads();
    }

    #pragma unroll
    for (int mi = 0; mi < 2; mi++)
    #pragma unroll
    for (int r = 0; r < 4; r++) {
        int row = m0 + mi*64 + ty*4 + r;
        #pragma unroll
        for (int ni = 0; ni < 2; ni++) {
            float4 v;
            v.x = acc[mi][ni][r][0]; v.y = acc[mi][ni][r][1];
            v.z = acc[mi][ni][r][2]; v.w = acc[mi][ni][r][3];
            *(float4*)(C + (size_t)row * N + n0 + ni*64 + tx*4) = v;
        }
    }
}

// ---------------------------------------------------------------------------
// MFMA flash attention. Block = (128 q-rows, one (b,h)). 512 thr = 8 waves,
// each wave owns 16 q-rows. KV tile 64. Dk=64.
//   QK^T : split-bf16 (hi+lo, 3 MFMAs) -> ~f32 accuracy; 1/8 scale folded
//          exactly into Q (power of two).
//   P*V  : fp16 single MFMA (P in [0,1], error ~2^-11 rel — within budget).
// LDS rows padded to 72 elems (144 B) -> <=2-way bank aliasing (free).
// ---------------------------------------------------------------------------
__global__ __launch_bounds__(512, 4)
void attn_mfma(const float* __restrict__ Qg, const float* __restrict__ Kg,
               const float* __restrict__ Vg, const int* __restrict__ mask,
               float* __restrict__ Og)
{
    const int S = 2048, E = 1024;
    __shared__ __bf16   Khi[64][72];
    __shared__ __bf16   Klo[64][72];
    __shared__ _Float16 Vt[64][72];     // [d][kv] transposed
    __shared__ _Float16 Ps[128][72];    // [q_local][kv_local], wave-partitioned

    const int tid  = threadIdx.x;
    const int lane = tid & 63;
    const int wid  = tid >> 6;          // 0..7
    const int l15  = lane & 15;
    const int lg   = lane >> 4;         // 0..3
    const int q0   = blockIdx.x * 128;
    const int h    = blockIdx.y;
    const int b    = blockIdx.z;
    const size_t base = (size_t)b * S * E + (size_t)h * 64;

    // ---- Q fragments in registers (scaled by 1/8, split hi/lo bf16) ----
    bf16x8 qh[2], ql[2];
    {
        const float* qp = Qg + base + (size_t)(q0 + wid*16 + l15) * E;
        #pragma unroll
        for (int kc = 0; kc < 2; kc++) {
            float4 v0 = *(const float4*)(qp + kc*32 + lg*8);
            float4 v1 = *(const float4*)(qp + kc*32 + lg*8 + 4);
            float xs[8] = {v0.x,v0.y,v0.z,v0.w,v1.x,v1.y,v1.z,v1.w};
            #pragma unroll
            for (int j = 0; j < 8; j++) {
                float x = xs[j] * 0.125f;
                __bf16 hh = (__bf16)x;
                qh[kc][j] = hh;
                ql[kc][j] = (__bf16)(x - (float)hh);
            }
        }
    }

    f32x4 o[4];
    #pragma unroll
    for (int nt = 0; nt < 4; nt++)
        #pragma unroll
        for (int r = 0; r < 4; r++) o[nt][r] = 0.f;
    float mrow[4], lrow[4];
    #pragma unroll
    for (int r = 0; r < 4; r++) { mrow[r] = -1e30f; lrow[r] = 0.f; }

    for (int k0 = 0; k0 < S; k0 += 64) {
        __syncthreads();   // previous iteration's PV reads done

        // ---- stage K (bf16 hi/lo) and V^T (fp16) ----
        #pragma unroll
        for (int i = 0; i < 2; i++) {
            int id  = tid + 512 * i;    // 0..1023
            int row = id >> 4;          // kv 0..63
            int c4  = id & 15;
            float4 kv4 = *(const float4*)(Kg + base + (size_t)(k0+row)*E + c4*4);
            float ks[4] = {kv4.x, kv4.y, kv4.z, kv4.w};
            bf16x4 kh, kl;
            #pragma unroll
            for (int j = 0; j < 4; j++) {
                __bf16 hh = (__bf16)ks[j];
                kh[j] = hh;
                kl[j] = (__bf16)(ks[j] - (float)hh);
            }
            *(bf16x4*)&Khi[row][c4*4] = kh;
            *(bf16x4*)&Klo[row][c4*4] = kl;
            float4 vv4 = *(const float4*)(Vg + base + (size_t)(k0+row)*E + c4*4);
            Vt[c4*4+0][row] = (_Float16)vv4.x;
            Vt[c4*4+1][row] = (_Float16)vv4.y;
            Vt[c4*4+2][row] = (_Float16)vv4.z;
            Vt[c4*4+3][row] = (_Float16)vv4.w;
        }
        __syncthreads();

        // ---- S = Q K^T (split bf16: hi*hi + lo*hi + hi*lo) ----
        f32x4 sf[4];
        #pragma unroll
        for (int nt = 0; nt < 4; nt++)
            #pragma unroll
            for (int r = 0; r < 4; r++) sf[nt][r] = 0.f;

        #pragma unroll
        for (int kc = 0; kc < 2; kc++)
            #pragma unroll
            for (int nt = 0; nt < 4; nt++) {
                bf16x8 kbh = *(const bf16x8*)&Khi[nt*16 + l15][kc*32 + lg*8];
                bf16x8 kbl = *(const bf16x8*)&Klo[nt*16 + l15][kc*32 + lg*8];
                sf[nt] = MFMA_BF16(qh[kc], kbh, sf[nt], 0, 0, 0);
                sf[nt] = MFMA_BF16(ql[kc], kbh, sf[nt], 0, 0, 0);
                sf[nt] = MFMA_BF16(qh[kc], kbl, sf[nt], 0, 0, 0);
            }

        // ---- key-padding mask ----
        #pragma unroll
        for (int nt = 0; nt < 4; nt++) {
            int mk = mask[b * S + k0 + nt*16 + l15];
            #pragma unroll
            for (int r = 0; r < 4; r++)
                sf[nt][r] = mk ? sf[nt][r] : -1e30f;
        }

        // ---- online softmax (rows live in 16-lane groups) ----
        #pragma unroll
        for (int r = 0; r < 4; r++) {
            float pm = fmaxf(fmaxf(sf[0][r], sf[1][r]), fmaxf(sf[2][r], sf[3][r]));
            #pragma unroll
            for (int d = 1; d < 16; d <<= 1) pm = fmaxf(pm, __shfl_xor(pm, d, 16));
            float mn   = fmaxf(mrow[r], pm);
            float corr = __expf(mrow[r] - mn);
            mrow[r] = mn;
            float p[4], rs = 0.f;
            #pragma unroll
            for (int nt = 0; nt < 4; nt++) { p[nt] = __expf(sf[nt][r] - mn); rs += p[nt]; }
            #pragma unroll
            for (int d = 1; d < 16; d <<= 1) rs += __shfl_xor(rs, d, 16);
            lrow[r] = lrow[r] * corr + rs;
            #pragma unroll
            for (int nt = 0; nt < 4; nt++) o[nt][r] *= corr;
            #pragma unroll
            for (int nt = 0; nt < 4; nt++)
                Ps[wid*16 + lg*4 + r][nt*16 + l15] = (_Float16)p[nt];
        }

        // wave-local LDS RAW fence (Ps is wave-partitioned; no block barrier)
        asm volatile("s_waitcnt lgkmcnt(0)" ::: "memory");

        // ---- O += P V (fp16 MFMA) ----
        #pragma unroll
        for (int kc = 0; kc < 2; kc++) {
            f16x8 pa = *(const f16x8*)&Ps[wid*16 + l15][kc*32 + lg*8];
            #pragma unroll
            for (int nt = 0; nt < 4; nt++) {
                f16x8 vb = *(const f16x8*)&Vt[nt*16 + l15][kc*32 + lg*8];
                o[nt] = MFMA_F16(pa, vb, o[nt], 0, 0, 0);
            }
        }
    }

    // ---- epilogue: normalize, store ----
    #pragma unroll
    for (int r = 0; r < 4; r++) {
        float inv = 1.0f / lrow[r];
        size_t rowoff = base + (size_t)(q0 + wid*16 + lg*4 + r) * E;
        #pragma unroll
        for (int nt = 0; nt < 4; nt++)
            Og[rowoff + nt*16 + l15] = o[nt][r] * inv;
    }
}

// ---------------------------------------------------------------------------
extern "C" void kernel_launch(void* const* d_in, const int* in_sizes, int n_in,
                              void* d_out, int out_size, void* d_ws, size_t ws_size,
                              hipStream_t stream)
{
    const float* x    = (const float*)d_in[0];
    const int*   mask = (const int*)  d_in[1];
    const float* Wq   = (const float*)d_in[2];
    const float* Wk   = (const float*)d_in[3];
    const float* Wv   = (const float*)d_in[4];
    const float* Wo   = (const float*)d_in[5];
    float* out = (float*)d_out;
    float* ws  = (float*)d_ws;

    const int B = 4, S = 2048, E = 1024;
    const int M = B * S;                 // 8192
    const size_t SZ = (size_t)M * E;     // 32 MB each

    float* Qb = ws;
    float* Kb = ws + SZ;
    float* Vb = ws + 2 * SZ;
    float* AO = Qb;   // safe alias: attn reads Q (h-slice) before writing it

    dim3 tb(256);
    dim3 gg(M / TM, E / TN);

    gemm_nt<<<gg, tb, 0, stream>>>(x, Wq, Qb, M, E, E);
    gemm_nt<<<gg, tb, 0, stream>>>(x, Wk, Kb, M, E, E);
    gemm_nt<<<gg, tb, 0, stream>>>(x, Wv, Vb, M, E, E);

    dim3 ga(S / 128, 16, B);             // 16 x 16 x 4 = 1024 blocks
    attn_mfma<<<ga, dim3(512), 0, stream>>>(Qb, Kb, Vb, mask, AO);

    gemm_nt<<<gg, tb, 0, stream>>>(AO, Wo, out, M, E, E);
}

// Round 3
// 661.654 us; speedup vs baseline: 2.8648x; 1.7252x over previous
//
#include <hip/hip_runtime.h>

typedef __attribute__((ext_vector_type(8))) __bf16   bf16x8;
typedef __attribute__((ext_vector_type(8))) _Float16 f16x8;
typedef __attribute__((ext_vector_type(4))) float    f32x4;

#define MFMA_BF16 __builtin_amdgcn_mfma_f32_16x16x32_bf16
#define MFMA_F16  __builtin_amdgcn_mfma_f32_16x16x32_f16

__device__ __forceinline__ void split_bf16(float x, __bf16& h, __bf16& l) {
    h = (__bf16)x;
    l = (__bf16)(x - (float)h);
}

// ---------------------------------------------------------------------------
// One-time f32 -> (hi, lo) bf16 planes. n8 = n/8.
// ---------------------------------------------------------------------------
__global__ __launch_bounds__(256)
void split_kernel(const float* __restrict__ src, __bf16* __restrict__ hi,
                  __bf16* __restrict__ lo, int n8)
{
    int i = blockIdx.x * 256 + threadIdx.x;
    if (i >= n8) return;
    float4 v0 = *(const float4*)(src + (size_t)i * 8);
    float4 v1 = *(const float4*)(src + (size_t)i * 8 + 4);
    float xs[8] = {v0.x, v0.y, v0.z, v0.w, v1.x, v1.y, v1.z, v1.w};
    bf16x8 h8, l8;
    #pragma unroll
    for (int j = 0; j < 8; j++) { __bf16 h, l; split_bf16(xs[j], h, l); h8[j] = h; l8[j] = l; }
    *(bf16x8*)(hi + (size_t)i * 8) = h8;
    *(bf16x8*)(lo + (size_t)i * 8) = l8;
}

// ---------------------------------------------------------------------------
// Split-bf16 MFMA GEMM: C[M,N] = A[M,K] * B[N,K]^T with A,B in (hi,lo) planes.
// 3 MFMAs (hh + lh + hl) ~ f32 accuracy. 128x128 tile, BK=32, 256 thr, 4 waves
// (2x2), 64x64 per wave. LDS pitch 40 bf16 (80 B) -> conflict-free b128 reads.
// MODE 0: f32 C.  MODE 1: split (hi,lo) C with scale.  MODE 2: f16 C.
// ---------------------------------------------------------------------------
template<int MODE>
__global__ __launch_bounds__(256, 4)
void gemm_split(const __bf16* __restrict__ Ahg, const __bf16* __restrict__ Alg,
                const __bf16* __restrict__ Bhg, const __bf16* __restrict__ Blg,
                float* __restrict__ Cf, __bf16* __restrict__ Chi,
                __bf16* __restrict__ Clo, _Float16* __restrict__ Ch,
                int M, int N, int K, float scale)
{
    const int P = 40;
    __shared__ __bf16 Ah[128][P], Al[128][P], Bh[128][P], Bl[128][P];

    const int t   = threadIdx.x;
    const int lane = t & 63;
    const int wid  = t >> 6;
    const int l15  = lane & 15;
    const int lg   = lane >> 4;
    const int wr   = wid >> 1, wc = wid & 1;
    const int m0 = blockIdx.x * 128, n0 = blockIdx.y * 128;

    f32x4 acc[4][4];
    #pragma unroll
    for (int i = 0; i < 4; i++)
        #pragma unroll
        for (int j = 0; j < 4; j++)
            #pragma unroll
            for (int r = 0; r < 4; r++) acc[i][j][r] = 0.f;

    for (int k0 = 0; k0 < K; k0 += 32) {
        __syncthreads();
        #pragma unroll
        for (int i = 0; i < 2; i++) {
            int id = t + 256 * i;
            int row = id >> 2, cc = id & 3;
            size_t ga = (size_t)(m0 + row) * K + k0 + cc * 8;
            size_t gb = (size_t)(n0 + row) * K + k0 + cc * 8;
            *(bf16x8*)&Ah[row][cc*8] = *(const bf16x8*)(Ahg + ga);
            *(bf16x8*)&Al[row][cc*8] = *(const bf16x8*)(Alg + ga);
            *(bf16x8*)&Bh[row][cc*8] = *(const bf16x8*)(Bhg + gb);
            *(bf16x8*)&Bl[row][cc*8] = *(const bf16x8*)(Blg + gb);
        }
        __syncthreads();

        bf16x8 ah[4], al[4];
        #pragma unroll
        for (int mr = 0; mr < 4; mr++) {
            ah[mr] = *(const bf16x8*)&Ah[wr*64 + mr*16 + l15][lg*8];
            al[mr] = *(const bf16x8*)&Al[wr*64 + mr*16 + l15][lg*8];
        }
        #pragma unroll
        for (int nr = 0; nr < 4; nr++) {
            bf16x8 bh = *(const bf16x8*)&Bh[wc*64 + nr*16 + l15][lg*8];
            bf16x8 bl = *(const bf16x8*)&Bl[wc*64 + nr*16 + l15][lg*8];
            #pragma unroll
            for (int mr = 0; mr < 4; mr++) {
                acc[mr][nr] = MFMA_BF16(ah[mr], bh, acc[mr][nr], 0, 0, 0);
                acc[mr][nr] = MFMA_BF16(al[mr], bh, acc[mr][nr], 0, 0, 0);
                acc[mr][nr] = MFMA_BF16(ah[mr], bl, acc[mr][nr], 0, 0, 0);
            }
        }
    }

    #pragma unroll
    for (int mr = 0; mr < 4; mr++)
    #pragma unroll
    for (int r = 0; r < 4; r++) {
        int row = m0 + wr*64 + mr*16 + lg*4 + r;
        #pragma unroll
        for (int nr = 0; nr < 4; nr++) {
            int col = n0 + wc*64 + nr*16 + l15;
            float v = acc[mr][nr][r] * scale;
            if constexpr (MODE == 0) {
                Cf[(size_t)row * N + col] = v;
            } else if constexpr (MODE == 1) {
                __bf16 h, l; split_bf16(v, h, l);
                Chi[(size_t)row * N + col] = h;
                Clo[(size_t)row * N + col] = l;
            } else {
                Ch[(size_t)row * N + col] = (_Float16)v;
            }
        }
    }
}

// ---------------------------------------------------------------------------
// MFMA flash attention on pre-split inputs. Block = 128 q-rows x one (b,h),
// 512 thr = 8 waves x 16 q-rows. KV tile 64, Dk 64.
//  - Q/K hi+lo bf16 (global, pre-split; Q pre-scaled by 1/8) -> 3-MFMA QK^T.
//  - V f16 (global, pre-converted); V^T in LDS with column-block XOR swizzle
//    c8' = c8 ^ (d>>3): transpose-writes AND b128 reads conflict-free.
//  - AO written as (hi,lo) bf16 for the final split GEMM.
// ---------------------------------------------------------------------------
__global__ __launch_bounds__(512, 6)
void attn_mfma(const __bf16* __restrict__ Qh_g, const __bf16* __restrict__ Ql_g,
               const __bf16* __restrict__ Kh_g, const __bf16* __restrict__ Kl_g,
               const _Float16* __restrict__ Vh_g, const int* __restrict__ mask,
               __bf16* __restrict__ AOh, __bf16* __restrict__ AOl)
{
    const int S = 2048, E = 1024;
    __shared__ __bf16   Khi[64][72];
    __shared__ __bf16   Klo[64][72];
    __shared__ _Float16 Vt[64][72];     // swizzled transpose: V[kv][d] at Vt[d][((kv>>3)^(d>>3))*8 + (kv&7)]
    __shared__ _Float16 Ps[128][72];

    const int tid  = threadIdx.x;
    const int lane = tid & 63;
    const int wid  = tid >> 6;
    const int l15  = lane & 15;
    const int lg   = lane >> 4;
    const int q0   = blockIdx.x * 128;
    const int h    = blockIdx.y;
    const int b    = blockIdx.z;
    const size_t base = (size_t)b * S * E + (size_t)h * 64;

    // Q fragments (already scaled by 1/8 and split)
    bf16x8 qh[2], ql[2];
    {
        size_t qoff = base + (size_t)(q0 + wid*16 + l15) * E;
        #pragma unroll
        for (int kc = 0; kc < 2; kc++) {
            qh[kc] = *(const bf16x8*)(Qh_g + qoff + kc*32 + lg*8);
            ql[kc] = *(const bf16x8*)(Ql_g + qoff + kc*32 + lg*8);
        }
    }

    f32x4 o[4];
    #pragma unroll
    for (int nt = 0; nt < 4; nt++)
        #pragma unroll
        for (int r = 0; r < 4; r++) o[nt][r] = 0.f;
    float mrow[4], lrow[4];
    #pragma unroll
    for (int r = 0; r < 4; r++) { mrow[r] = -1e30f; lrow[r] = 0.f; }

    const int srow = tid >> 3;          // 0..63 staging row
    const int scc  = tid & 7;           // 0..7  staging 8-elem chunk

    for (int k0 = 0; k0 < S; k0 += 64) {
        __syncthreads();   // previous iteration's LDS reads done

        {   // stage K planes (1 chunk per thread per plane) + swizzled V^T
            size_t goff = base + (size_t)(k0 + srow) * E + scc * 8;
            *(bf16x8*)&Khi[srow][scc*8] = *(const bf16x8*)(Kh_g + goff);
            *(bf16x8*)&Klo[srow][scc*8] = *(const bf16x8*)(Kl_g + goff);
            f16x8 v8 = *(const f16x8*)(Vh_g + goff);
            int cbase = ((srow >> 3) ^ scc) * 8 + (srow & 7);
            #pragma unroll
            for (int j = 0; j < 8; j++)
                Vt[scc*8 + j][cbase] = v8[j];
        }
        __syncthreads();

        // S = Q K^T (hh + lh + hl)
        f32x4 sf[4];
        #pragma unroll
        for (int nt = 0; nt < 4; nt++)
            #pragma unroll
            for (int r = 0; r < 4; r++) sf[nt][r] = 0.f;

        #pragma unroll
        for (int kc = 0; kc < 2; kc++)
            #pragma unroll
            for (int nt = 0; nt < 4; nt++) {
                bf16x8 kbh = *(const bf16x8*)&Khi[nt*16 + l15][kc*32 + lg*8];
                bf16x8 kbl = *(const bf16x8*)&Klo[nt*16 + l15][kc*32 + lg*8];
                sf[nt] = MFMA_BF16(qh[kc], kbh, sf[nt], 0, 0, 0);
                sf[nt] = MFMA_BF16(ql[kc], kbh, sf[nt], 0, 0, 0);
                sf[nt] = MFMA_BF16(qh[kc], kbl, sf[nt], 0, 0, 0);
            }

        // key-padding mask
        #pragma unroll
        for (int nt = 0; nt < 4; nt++) {
            int mk = mask[b * S + k0 + nt*16 + l15];
            #pragma unroll
            for (int r = 0; r < 4; r++)
                sf[nt][r] = mk ? sf[nt][r] : -1e30f;
        }

        // online softmax (16 lanes per row)
        #pragma unroll
        for (int r = 0; r < 4; r++) {
            float pm = fmaxf(fmaxf(sf[0][r], sf[1][r]), fmaxf(sf[2][r], sf[3][r]));
            #pragma unroll
            for (int d = 1; d < 16; d <<= 1) pm = fmaxf(pm, __shfl_xor(pm, d, 16));
            float mn   = fmaxf(mrow[r], pm);
            float corr = __expf(mrow[r] - mn);
            mrow[r] = mn;
            float p[4], rs = 0.f;
            #pragma unroll
            for (int nt = 0; nt < 4; nt++) { p[nt] = __expf(sf[nt][r] - mn); rs += p[nt]; }
            #pragma unroll
            for (int d = 1; d < 16; d <<= 1) rs += __shfl_xor(rs, d, 16);
            lrow[r] = lrow[r] * corr + rs;
            #pragma unroll
            for (int nt = 0; nt < 4; nt++) o[nt][r] *= corr;
            #pragma unroll
            for (int nt = 0; nt < 4; nt++)
                Ps[wid*16 + lg*4 + r][nt*16 + l15] = (_Float16)p[nt];
        }

        // wave-local RAW fence (Ps rows are wave-private)
        asm volatile("s_waitcnt lgkmcnt(0)" ::: "memory");

        // O += P V  (f16 MFMA; V^T read back through the same swizzle)
        #pragma unroll
        for (int kc = 0; kc < 2; kc++) {
            f16x8 pa = *(const f16x8*)&Ps[wid*16 + l15][kc*32 + lg*8];
            #pragma unroll
            for (int nt = 0; nt < 4; nt++) {
                int c8p = (kc*4 + lg) ^ (nt*2 + (l15 >> 3));
                f16x8 vb = *(const f16x8*)&Vt[nt*16 + l15][c8p*8];
                o[nt] = MFMA_F16(pa, vb, o[nt], 0, 0, 0);
            }
        }
    }

    // epilogue: normalize + split-store AO (aliases Q planes: block-private rows)
    #pragma unroll
    for (int r = 0; r < 4; r++) {
        float inv = 1.0f / lrow[r];
        size_t rowoff = base + (size_t)(q0 + wid*16 + lg*4 + r) * E;
        #pragma unroll
        for (int nt = 0; nt < 4; nt++) {
            __bf16 hh, ll;
            split_bf16(o[nt][r] * inv, hh, ll);
            AOh[rowoff + nt*16 + l15] = hh;
            AOl[rowoff + nt*16 + l15] = ll;
        }
    }
}

// ---------------------------------------------------------------------------
extern "C" void kernel_launch(void* const* d_in, const int* in_sizes, int n_in,
                              void* d_out, int out_size, void* d_ws, size_t ws_size,
                              hipStream_t stream)
{
    const float* x    = (const float*)d_in[0];
    const int*   mask = (const int*)  d_in[1];
    const float* Wq   = (const float*)d_in[2];
    const float* Wk   = (const float*)d_in[3];
    const float* Wv   = (const float*)d_in[4];
    const float* Wo   = (const float*)d_in[5];
    float* out = (float*)d_out;

    const int B = 4, S = 2048, E = 1024;
    const int M = B * S;                          // 8192
    const size_t SZ  = (size_t)M * E;             // 8388608 elems
    const size_t WSZ = (size_t)E * E;             // 1048576 elems
    const size_t PB  = SZ * sizeof(__bf16);       // 16 MB per plane

    // x planes live in d_out (exactly 2 planes); dead before final GEMM writes out
    __bf16* xhi = (__bf16*)d_out;
    __bf16* xlo = xhi + SZ;

    char* ws = (char*)d_ws;
    __bf16*   qhi = (__bf16*)(ws);
    __bf16*   qlo = (__bf16*)(ws + PB);
    __bf16*   khi = (__bf16*)(ws + 2*PB);
    __bf16*   klo = (__bf16*)(ws + 3*PB);
    _Float16* vh  = (_Float16*)(ws + 4*PB);       // 16 MB
    __bf16*   wh  = (__bf16*)(ws + 5*PB);         // 2 MB
    __bf16*   wl  = (__bf16*)(ws + 5*PB + WSZ*sizeof(__bf16));

    const int n8x = (int)(SZ / 8);                // 1048576
    const int n8w = (int)(WSZ / 8);               // 131072

    split_kernel<<<n8x/256, 256, 0, stream>>>(x, xhi, xlo, n8x);

    dim3 gg(M/128, E/128);                        // 64 x 8
    dim3 tb(256);

    split_kernel<<<n8w/256, 256, 0, stream>>>(Wq, wh, wl, n8w);
    gemm_split<1><<<gg, tb, 0, stream>>>(xhi, xlo, wh, wl,
        nullptr, qhi, qlo, nullptr, M, E, E, 0.125f);   // exact 1/sqrt(64) folded

    split_kernel<<<n8w/256, 256, 0, stream>>>(Wk, wh, wl, n8w);
    gemm_split<1><<<gg, tb, 0, stream>>>(xhi, xlo, wh, wl,
        nullptr, khi, klo, nullptr, M, E, E, 1.0f);

    split_kernel<<<n8w/256, 256, 0, stream>>>(Wv, wh, wl, n8w);
    gemm_split<2><<<gg, tb, 0, stream>>>(xhi, xlo, wh, wl,
        nullptr, nullptr, nullptr, vh, M, E, E, 1.0f);

    split_kernel<<<n8w/256, 256, 0, stream>>>(Wo, wh, wl, n8w);  // before attn; buffer free

    dim3 ga(S/128, 16, B);                        // 16 x 16 x 4 = 1024 blocks
    attn_mfma<<<ga, dim3(512), 0, stream>>>(qhi, qlo, khi, klo, vh, mask,
                                            qhi, qlo);  // AO aliases Q planes

    gemm_split<0><<<gg, tb, 0, stream>>>(qhi, qlo, wh, wl,
        out, nullptr, nullptr, nullptr, M, E, E, 1.0f);
}

// Round 4
// 539.782 us; speedup vs baseline: 3.5116x; 1.2258x over previous
//
#include <hip/hip_runtime.h>

typedef __attribute__((ext_vector_type(8))) __bf16   bf16x8;
typedef __attribute__((ext_vector_type(8))) _Float16 f16x8;
typedef __attribute__((ext_vector_type(4))) float    f32x4;

#define MFMA_BF16 __builtin_amdgcn_mfma_f32_16x16x32_bf16
#define MFMA_F16  __builtin_amdgcn_mfma_f32_16x16x32_f16

__device__ __forceinline__ void split_bf16(float x, __bf16& h, __bf16& l) {
    h = (__bf16)x;
    l = (__bf16)(x - (float)h);
}

// ---------------------------------------------------------------------------
// One-time f32 -> (hi, lo) bf16 planes. n8 = n/8.
// ---------------------------------------------------------------------------
__global__ __launch_bounds__(256)
void split_kernel(const float* __restrict__ src, __bf16* __restrict__ hi,
                  __bf16* __restrict__ lo, int n8)
{
    int i = blockIdx.x * 256 + threadIdx.x;
    if (i >= n8) return;
    float4 v0 = *(const float4*)(src + (size_t)i * 8);
    float4 v1 = *(const float4*)(src + (size_t)i * 8 + 4);
    float xs[8] = {v0.x, v0.y, v0.z, v0.w, v1.x, v1.y, v1.z, v1.w};
    bf16x8 h8, l8;
    #pragma unroll
    for (int j = 0; j < 8; j++) { __bf16 h, l; split_bf16(xs[j], h, l); h8[j] = h; l8[j] = l; }
    *(bf16x8*)(hi + (size_t)i * 8) = h8;
    *(bf16x8*)(lo + (size_t)i * 8) = l8;
}

// ---------------------------------------------------------------------------
// Split-bf16 MFMA GEMM: C[M,N] = A[M,K] * B[N,K]^T with A,B in (hi,lo) planes.
// 3 MFMAs (hh + lh + hl) ~ f32 accuracy. 128x128 tile, BK=32, 256 thr, 4 waves
// (2x2), 64x64 per wave. LDS pitch 40 bf16 (80 B) -> conflict-free b128 reads.
// MODE 0: f32 C.  MODE 1: split (hi,lo) C with scale.  MODE 2: f16 C.
// ---------------------------------------------------------------------------
template<int MODE>
__global__ __launch_bounds__(256, 4)
void gemm_split(const __bf16* __restrict__ Ahg, const __bf16* __restrict__ Alg,
                const __bf16* __restrict__ Bhg, const __bf16* __restrict__ Blg,
                float* __restrict__ Cf, __bf16* __restrict__ Chi,
                __bf16* __restrict__ Clo, _Float16* __restrict__ Ch,
                int M, int N, int K, float scale)
{
    const int P = 40;
    __shared__ __bf16 Ah[128][P], Al[128][P], Bh[128][P], Bl[128][P];

    const int t   = threadIdx.x;
    const int lane = t & 63;
    const int wid  = t >> 6;
    const int l15  = lane & 15;
    const int lg   = lane >> 4;
    const int wr   = wid >> 1, wc = wid & 1;
    const int m0 = blockIdx.x * 128, n0 = blockIdx.y * 128;

    f32x4 acc[4][4];
    #pragma unroll
    for (int i = 0; i < 4; i++)
        #pragma unroll
        for (int j = 0; j < 4; j++)
            #pragma unroll
            for (int r = 0; r < 4; r++) acc[i][j][r] = 0.f;

    for (int k0 = 0; k0 < K; k0 += 32) {
        __syncthreads();
        #pragma unroll
        for (int i = 0; i < 2; i++) {
            int id = t + 256 * i;
            int row = id >> 2, cc = id & 3;
            size_t ga = (size_t)(m0 + row) * K + k0 + cc * 8;
            size_t gb = (size_t)(n0 + row) * K + k0 + cc * 8;
            *(bf16x8*)&Ah[row][cc*8] = *(const bf16x8*)(Ahg + ga);
            *(bf16x8*)&Al[row][cc*8] = *(const bf16x8*)(Alg + ga);
            *(bf16x8*)&Bh[row][cc*8] = *(const bf16x8*)(Bhg + gb);
            *(bf16x8*)&Bl[row][cc*8] = *(const bf16x8*)(Blg + gb);
        }
        __syncthreads();

        bf16x8 ah[4], al[4];
        #pragma unroll
        for (int mr = 0; mr < 4; mr++) {
            ah[mr] = *(const bf16x8*)&Ah[wr*64 + mr*16 + l15][lg*8];
            al[mr] = *(const bf16x8*)&Al[wr*64 + mr*16 + l15][lg*8];
        }
        #pragma unroll
        for (int nr = 0; nr < 4; nr++) {
            bf16x8 bh = *(const bf16x8*)&Bh[wc*64 + nr*16 + l15][lg*8];
            bf16x8 bl = *(const bf16x8*)&Bl[wc*64 + nr*16 + l15][lg*8];
            #pragma unroll
            for (int mr = 0; mr < 4; mr++) {
                acc[mr][nr] = MFMA_BF16(ah[mr], bh, acc[mr][nr], 0, 0, 0);
                acc[mr][nr] = MFMA_BF16(al[mr], bh, acc[mr][nr], 0, 0, 0);
                acc[mr][nr] = MFMA_BF16(ah[mr], bl, acc[mr][nr], 0, 0, 0);
            }
        }
    }

    #pragma unroll
    for (int mr = 0; mr < 4; mr++)
    #pragma unroll
    for (int r = 0; r < 4; r++) {
        int row = m0 + wr*64 + mr*16 + lg*4 + r;
        #pragma unroll
        for (int nr = 0; nr < 4; nr++) {
            int col = n0 + wc*64 + nr*16 + l15;
            float v = acc[mr][nr][r] * scale;
            if constexpr (MODE == 0) {
                Cf[(size_t)row * N + col] = v;
            } else if constexpr (MODE == 1) {
                __bf16 h, l; split_bf16(v, h, l);
                Chi[(size_t)row * N + col] = h;
                Clo[(size_t)row * N + col] = l;
            } else {
                Ch[(size_t)row * N + col] = (_Float16)v;
            }
        }
    }
}

// ---------------------------------------------------------------------------
// MFMA flash attention on pre-split inputs. Block = 256 q-rows x one (b,h),
// 1024 thr = 16 waves x 16 q-rows. KV tile 64, Dk 64.
//  - Q/K hi+lo bf16 (pre-split; Q pre-scaled by 1/8) -> 3-MFMA QK^T.
//  - V f16; V^T in LDS with column-block XOR swizzle (writes+reads clean).
//  - XCD-clustered flat grid: all q-blocks of one (b,h) on one XCD L2.
//  - AO written as (hi,lo) bf16 via LDS bounce -> fully coalesced 16B stores.
// ---------------------------------------------------------------------------
__global__ __launch_bounds__(1024, 4)
void attn_mfma(const __bf16* __restrict__ Qh_g, const __bf16* __restrict__ Ql_g,
               const __bf16* __restrict__ Kh_g, const __bf16* __restrict__ Kl_g,
               const _Float16* __restrict__ Vh_g, const int* __restrict__ mask,
               __bf16* AOh, __bf16* AOl)
{
    const int S = 2048, E = 1024;
    __shared__ __bf16   Khi[64][72];
    __shared__ __bf16   Klo[64][72];
    __shared__ _Float16 Vt[64][72];
    __shared__ _Float16 Ps[256][72];

    const int tid  = threadIdx.x;
    const int lane = tid & 63;
    const int wid  = tid >> 6;          // 0..15
    const int l15  = lane & 15;
    const int lg   = lane >> 4;

    // XCD-clustered decode: fid -> (qb, h, b)
    const int fid = blockIdx.x;         // 0..511
    const int xcd = fid & 7;
    const int j   = fid >> 3;           // 0..63
    const int bh  = xcd * 8 + (j >> 3); // 0..63
    const int qb  = j & 7;
    const int h   = bh & 15;
    const int b   = bh >> 4;
    const int q0  = qb * 256;
    const size_t base = (size_t)b * S * E + (size_t)h * 64;

    // Q fragments (already scaled by 1/8 and split)
    bf16x8 qh[2], ql[2];
    {
        size_t qoff = base + (size_t)(q0 + wid*16 + l15) * E;
        #pragma unroll
        for (int kc = 0; kc < 2; kc++) {
            qh[kc] = *(const bf16x8*)(Qh_g + qoff + kc*32 + lg*8);
            ql[kc] = *(const bf16x8*)(Ql_g + qoff + kc*32 + lg*8);
        }
    }

    f32x4 o[4];
    #pragma unroll
    for (int nt = 0; nt < 4; nt++)
        #pragma unroll
        for (int r = 0; r < 4; r++) o[nt][r] = 0.f;
    float mrow[4], lrow[4];
    #pragma unroll
    for (int r = 0; r < 4; r++) { mrow[r] = -1e30f; lrow[r] = 0.f; }

    for (int k0 = 0; k0 < S; k0 += 64) {
        __syncthreads();   // previous iteration's LDS reads done

        // stage: tid<512 -> K hi/lo planes; tid>=512 -> swizzled V^T
        if (tid < 512) {
            int row = tid >> 3, scc = tid & 7;
            size_t goff = base + (size_t)(k0 + row) * E + scc * 8;
            *(bf16x8*)&Khi[row][scc*8] = *(const bf16x8*)(Kh_g + goff);
            *(bf16x8*)&Klo[row][scc*8] = *(const bf16x8*)(Kl_g + goff);
        } else {
            int t2 = tid - 512;
            int row = t2 >> 3, scc = t2 & 7;
            size_t goff = base + (size_t)(k0 + row) * E + scc * 8;
            f16x8 v8 = *(const f16x8*)(Vh_g + goff);
            int cbase = ((row >> 3) ^ scc) * 8 + (row & 7);
            #pragma unroll
            for (int jj = 0; jj < 8; jj++)
                Vt[scc*8 + jj][cbase] = v8[jj];
        }
        __syncthreads();

        // S = Q K^T (hh + lh + hl)
        f32x4 sf[4];
        #pragma unroll
        for (int nt = 0; nt < 4; nt++)
            #pragma unroll
            for (int r = 0; r < 4; r++) sf[nt][r] = 0.f;

        #pragma unroll
        for (int kc = 0; kc < 2; kc++)
            #pragma unroll
            for (int nt = 0; nt < 4; nt++) {
                bf16x8 kbh = *(const bf16x8*)&Khi[nt*16 + l15][kc*32 + lg*8];
                bf16x8 kbl = *(const bf16x8*)&Klo[nt*16 + l15][kc*32 + lg*8];
                sf[nt] = MFMA_BF16(qh[kc], kbh, sf[nt], 0, 0, 0);
                sf[nt] = MFMA_BF16(ql[kc], kbh, sf[nt], 0, 0, 0);
                sf[nt] = MFMA_BF16(qh[kc], kbl, sf[nt], 0, 0, 0);
            }

        // key-padding mask
        #pragma unroll
        for (int nt = 0; nt < 4; nt++) {
            int mk = mask[b * S + k0 + nt*16 + l15];
            #pragma unroll
            for (int r = 0; r < 4; r++)
                sf[nt][r] = mk ? sf[nt][r] : -1e30f;
        }

        // online softmax (16 lanes per row)
        #pragma unroll
        for (int r = 0; r < 4; r++) {
            float pm = fmaxf(fmaxf(sf[0][r], sf[1][r]), fmaxf(sf[2][r], sf[3][r]));
            #pragma unroll
            for (int d = 1; d < 16; d <<= 1) pm = fmaxf(pm, __shfl_xor(pm, d, 16));
            float mn   = fmaxf(mrow[r], pm);
            float corr = __expf(mrow[r] - mn);
            mrow[r] = mn;
            float p[4], rs = 0.f;
            #pragma unroll
            for (int nt = 0; nt < 4; nt++) { p[nt] = __expf(sf[nt][r] - mn); rs += p[nt]; }
            #pragma unroll
            for (int d = 1; d < 16; d <<= 1) rs += __shfl_xor(rs, d, 16);
            lrow[r] = lrow[r] * corr + rs;
            #pragma unroll
            for (int nt = 0; nt < 4; nt++) o[nt][r] *= corr;
            #pragma unroll
            for (int nt = 0; nt < 4; nt++)
                Ps[wid*16 + lg*4 + r][nt*16 + l15] = (_Float16)p[nt];
        }

        // wave-local RAW fence (Ps rows are wave-private); pin MFMA after it
        asm volatile("s_waitcnt lgkmcnt(0)" ::: "memory");
        __builtin_amdgcn_sched_barrier(0);

        // O += P V  (f16 MFMA; V^T read back through the same swizzle)
        #pragma unroll
        for (int kc = 0; kc < 2; kc++) {
            f16x8 pa = *(const f16x8*)&Ps[wid*16 + l15][kc*32 + lg*8];
            #pragma unroll
            for (int nt = 0; nt < 4; nt++) {
                int c8p = (kc*4 + lg) ^ (nt*2 + (l15 >> 3));
                f16x8 vb = *(const f16x8*)&Vt[nt*16 + l15][c8p*8];
                o[nt] = MFMA_F16(pa, vb, o[nt], 0, 0, 0);
            }
        }
    }

    // ---- epilogue: normalize + split, bounce through Ps for coalesced 16B stores
    unsigned short* Pu = (unsigned short*)&Ps[0][0];   // raw 2B view, pitch 72
    float inv[4];
    #pragma unroll
    for (int r = 0; r < 4; r++) inv[r] = 1.0f / lrow[r];

    #pragma unroll
    for (int plane = 0; plane < 2; plane++) {
        __syncthreads();   // previous reads of Ps done
        #pragma unroll
        for (int r = 0; r < 4; r++)
            #pragma unroll
            for (int nt = 0; nt < 4; nt++) {
                float v = o[nt][r] * inv[r];
                __bf16 hh, ll; split_bf16(v, hh, ll);
                __bf16 sv = plane == 0 ? hh : ll;
                Pu[(wid*16 + lg*4 + r) * 72 + nt*16 + l15] =
                    *(unsigned short*)&sv;
            }
        __syncthreads();
        __bf16* dst = plane == 0 ? AOh : AOl;
        #pragma unroll
        for (int i = 0; i < 2; i++) {
            int u   = tid + 1024 * i;     // 0..2047
            int row = u >> 3, c8 = u & 7;
            bf16x8 v8;
            #pragma unroll
            for (int jj = 0; jj < 8; jj++) {
                unsigned short us = Pu[row * 72 + c8*8 + jj];
                v8[jj] = *(__bf16*)&us;
            }
            *(bf16x8*)(dst + base + (size_t)(q0 + row) * E + c8 * 8) = v8;
        }
    }
}

// ---------------------------------------------------------------------------
extern "C" void kernel_launch(void* const* d_in, const int* in_sizes, int n_in,
                              void* d_out, int out_size, void* d_ws, size_t ws_size,
                              hipStream_t stream)
{
    const float* x    = (const float*)d_in[0];
    const int*   mask = (const int*)  d_in[1];
    const float* Wq   = (const float*)d_in[2];
    const float* Wk   = (const float*)d_in[3];
    const float* Wv   = (const float*)d_in[4];
    const float* Wo   = (const float*)d_in[5];
    float* out = (float*)d_out;

    const int B = 4, S = 2048, E = 1024;
    const int M = B * S;                          // 8192
    const size_t SZ  = (size_t)M * E;
    const size_t WSZ = (size_t)E * E;
    const size_t PB  = SZ * sizeof(__bf16);       // 16 MB per plane

    __bf16* xhi = (__bf16*)d_out;                 // x planes live in d_out
    __bf16* xlo = xhi + SZ;

    char* ws = (char*)d_ws;
    __bf16*   qhi = (__bf16*)(ws);
    __bf16*   qlo = (__bf16*)(ws + PB);
    __bf16*   khi = (__bf16*)(ws + 2*PB);
    __bf16*   klo = (__bf16*)(ws + 3*PB);
    _Float16* vh  = (_Float16*)(ws + 4*PB);
    __bf16*   wh  = (__bf16*)(ws + 5*PB);
    __bf16*   wl  = (__bf16*)(ws + 5*PB + WSZ*sizeof(__bf16));

    const int n8x = (int)(SZ / 8);
    const int n8w = (int)(WSZ / 8);

    split_kernel<<<n8x/256, 256, 0, stream>>>(x, xhi, xlo, n8x);

    dim3 gg(M/128, E/128);
    dim3 tb(256);

    split_kernel<<<n8w/256, 256, 0, stream>>>(Wq, wh, wl, n8w);
    gemm_split<1><<<gg, tb, 0, stream>>>(xhi, xlo, wh, wl,
        nullptr, qhi, qlo, nullptr, M, E, E, 0.125f);   // exact 1/sqrt(64)

    split_kernel<<<n8w/256, 256, 0, stream>>>(Wk, wh, wl, n8w);
    gemm_split<1><<<gg, tb, 0, stream>>>(xhi, xlo, wh, wl,
        nullptr, khi, klo, nullptr, M, E, E, 1.0f);

    split_kernel<<<n8w/256, 256, 0, stream>>>(Wv, wh, wl, n8w);
    gemm_split<2><<<gg, tb, 0, stream>>>(xhi, xlo, wh, wl,
        nullptr, nullptr, nullptr, vh, M, E, E, 1.0f);

    split_kernel<<<n8w/256, 256, 0, stream>>>(Wo, wh, wl, n8w);  // before attn

    attn_mfma<<<dim3(512), dim3(1024), 0, stream>>>(qhi, qlo, khi, klo, vh, mask,
                                                    qhi, qlo);   // AO aliases Q

    gemm_split<0><<<gg, tb, 0, stream>>>(qhi, qlo, wh, wl,
        out, nullptr, nullptr, nullptr, M, E, E, 1.0f);
}